// Round 6
// baseline (253.498 us; speedup 1.0000x reference)
//
#include <hip/hip_runtime.h>

// Problem constants (fixed by reference)
#define CC 32
#define HH 256
#define WW 512
#define NN 4
#define MAXD 48

// Round-6 structure: BOTH operands in LDS; main loop has ZERO global ops.
//
// Evidence trail: rounds 0/5 identical 96 us across occupancy/VGPR changes,
// VALUBusy pinned ~19% -> main-loop global L load (2-deep prefetch vs
// ~500-900 cyc latency) is the binder, not occupancy. Fix: stage L (32 KB,
// once) + R (19 KB, two 16-channel halves) in LDS; per channel the loop is
// 4 ds_read_b128 + 32 FMA, fully compiler-pipelineable via ds offset imms.
//
// LDS = 32*256*4 + 16*304*4 = 52224 B <= 64 KB/block -> 3 blocks/CU.
// 384 threads = 64 w-groups x 6 d-groups (dg = t>>6 wave-uniform).
// VGPR: acc 32 + rv 12 + lf 4 + temps ~= 65; budget 80 (launch_bounds 384,6)
// -> no spill (round-3/4 lesson: check WRITE_SIZE ~= 101 MB to confirm).
#define WT 256
#define RW (WT + MAXD)    // 304 r columns staged (w0-48 .. w0+255)
#define CH 16             // r channels per staging pass (2 passes)
#define DTILE 8           // d per thread; d0 = 8*dg (mult of 4 -> aligned window)
#define WTILE 4           // w per thread; wb mult of 4 -> aligned float4
#define NT 384            // 6 waves/block

__global__ __launch_bounds__(NT, 6)
void cost_volume_kernel(const float* __restrict__ L,
                        const float* __restrict__ R,
                        float* __restrict__ out)
{
    __shared__ float l_s[CC][WT];        // 32 KB, all channels, staged once
    __shared__ float r_s[CH][RW];        // 19 KB, 16 channels per half

    const int t  = threadIdx.x;          // 0..383
    const int w0 = blockIdx.x * WT;      // 0 or 256
    const int h  = blockIdx.y;
    const int n  = blockIdx.z;

    const size_t chw  = (size_t)HH * WW;                       // channel stride
    const size_t rowB = (size_t)n * CC * chw + (size_t)h * WW; // (n, c=0, h, 0)

    const int wg = t & 63;               // lane; dg wave-uniform
    const int dg = t >> 6;               // 0..5
    const int wb = wg * WTILE;           // 0..252, multiple of 4
    const int d0 = dg * DTILE;           // 0,8,16,24,32,40
    // r_s col for (local w=wb+i, d=d0+k) is wb+i+48-d0-k, i in [0,3], k in [0,7]
    // -> window [wb+41-d0, wb+51-d0]; aligned 12-float superset starts at:
    const int jA = wb + 40 - d0;         // multiple of 4; 0..292, +11 <= 303

    float acc[DTILE][WTILE];
    #pragma unroll
    for (int k = 0; k < DTILE; ++k)
        #pragma unroll
        for (int i = 0; i < WTILE; ++i)
            acc[k][i] = 0.f;

    // ---- stage L: 32 rows x 64 float4 = 2048 slots, coalesced, independent
    #pragma unroll
    for (int k = 0; k < 6; ++k) {
        int idx = t + NT * k;            // 0..2303
        if (idx < CC * 64) {
            int c  = idx >> 6;           // 64 float4 per row
            int j4 = idx & 63;
            *(float4*)&l_s[c][4 * j4] =
                *(const float4*)(L + rowB + (size_t)c * chw + w0 + 4 * j4);
        }
    }

    for (int half = 0; half < 2; ++half) {
        const int c0 = half * CH;
        if (half) __syncthreads();       // drain half-0 compute before restage

        // ---- stage R half: 16 rows x 76 float4 = 1216 slots, coalesced
        #pragma unroll
        for (int k = 0; k < 4; ++k) {
            int idx = t + NT * k;        // 0..1535
            if (idx < CH * 76) {
                int c   = idx / 76;      // 76 float4 per row
                int j4  = idx - c * 76;
                int g   = w0 - MAXD + 4 * j4;    // global w of this float4
                float4 v = make_float4(0.f, 0.f, 0.f, 0.f);
                if (g >= 0)              // w<0 -> zeros (zero pad / w<d)
                    v = *(const float4*)(R + rowB + (size_t)(c0 + c) * chw + g);
                *(float4*)&r_s[c][4 * j4] = v;
            }
        }
        __syncthreads();

        #pragma unroll 4
        for (int cc = 0; cc < CH; ++cc) {
            const int c = c0 + cc;
            float lf[4];
            *(float4*)lf = *(const float4*)&l_s[c][wb];
            float rv[12];
            #pragma unroll
            for (int q = 0; q < 3; ++q)
                *(float4*)&rv[4 * q] = *(const float4*)&r_s[cc][jA + 4 * q];
            #pragma unroll
            for (int k = 0; k < DTILE; ++k) {
                acc[k][0] += lf[0] * rv[8 - k];   // offsets 1..11, compile-time
                acc[k][1] += lf[1] * rv[9 - k];
                acc[k][2] += lf[2] * rv[10 - k];
                acc[k][3] += lf[3] * rv[11 - k];
            }
        }
    }

    const float inv = 1.0f / 32.0f;      // mean over C, exact pow2
    #pragma unroll
    for (int k = 0; k < DTILE; ++k) {
        const int d = d0 + k;
        float4 o = make_float4(acc[k][0] * inv, acc[k][1] * inv,
                               acc[k][2] * inv, acc[k][3] * inv);
        *(float4*)(out + (((size_t)n * MAXD + d) * HH + h) * WW + w0 + wb) = o;
    }
}

extern "C" void kernel_launch(void* const* d_in, const int* in_sizes, int n_in,
                              void* d_out, int out_size, void* d_ws, size_t ws_size,
                              hipStream_t stream) {
    const float* L = (const float*)d_in[0];
    const float* R = (const float*)d_in[1];
    float* out = (float*)d_out;
    // d_in[2] (use_naive) is ignored per reference.
    dim3 grid(WW / WT, HH, NN);          // 2 x 256 x 4 = 2048 blocks
    cost_volume_kernel<<<grid, dim3(NT, 1, 1), 0, stream>>>(L, R, out);
}